// Round 3
// baseline (326.476 us; speedup 1.0000x reference)
//
#include <hip/hip_runtime.h>
#include <hip/hip_bf16.h>
#include <stdint.h>

#define KN 32
#define D  128
#define NNODES 20000
#define GRID 2500
#define ITERS 4            // 2 nodes/iter * 4 iters * 2500 blocks = 20000

typedef __bf16 bf16;
typedef __bf16 bf16x8 __attribute__((ext_vector_type(8)));
typedef float  f32x4  __attribute__((ext_vector_type(4)));

// e_u LDS layout: 16 chunks/node; chunk c = rows (c, c+16) back-to-back (1024 B,
// written by ONE global_load_lds wave-instruction) + 16 B pad -> 1040 B chunk.
// 1040 B = 260 dw, 260 % 32 = 4 -> row bank-granule rotates by 1 per chunk:
// A-frag b128 reads have distinct granules within each 8-lane group (conflict-free).
#define CHUNK_DW 260
#define EU_NODE_DW (16 * CHUNK_DW)   // 4160 dw per node
#define H_STRIDE 136                 // bf16 elems; 68 dw, %32=4 -> rotates, b128-clean

#define GL2LDS(src, dst) __builtin_amdgcn_global_load_lds(                 \
    (const __attribute__((address_space(1))) void*)(src),                  \
    (__attribute__((address_space(3))) void*)(dst), 16, 0, 0)

#define MFMA(a, b, c) __builtin_amdgcn_mfma_f32_16x16x32_bf16((a), (b), (c), 0, 0, 0)

// ---------------------------------------------------------------------------
// Pack W1 (128x256) and W2 (128x128) fp32 -> bf16 in MFMA B-fragment order.
// B-frag for mfma_f32_16x16x32_bf16: lane holds B[k=quad*8+j][n=lane&15].
// ---------------------------------------------------------------------------
__global__ __launch_bounds__(256) void pack_weights_kernel(
    const float* __restrict__ W1, const float* __restrict__ W2,
    bf16* __restrict__ w1p, bf16* __restrict__ w2p)
{
    int t = blockIdx.x * 256 + threadIdx.x;
    if (t < 32768) {
        int j = t & 7, lane = (t >> 3) & 63, kt = (t >> 9) & 7, nt = t >> 12;
        int d = nt * 16 + (lane & 15);
        int f = kt * 32 + ((lane >> 4) << 3) + j;
        w1p[t] = (bf16)W1[d * 256 + f];
    } else if (t < 49152) {
        int u = t - 32768;
        int j = u & 7, lane = (u >> 3) & 63, kt = (u >> 9) & 3, nt = u >> 11;
        int e  = nt * 16 + (lane & 15);
        int dd = kt * 32 + ((lane >> 4) << 3) + j;
        w2p[u] = (bf16)W2[e * 128 + dd];
    }
}

// ---------------------------------------------------------------------------
// 256 threads = 4 waves; 2 nodes per iteration, 8 nodes per block.
// Weights resident in registers (AGPR side of the unified file).
// ---------------------------------------------------------------------------
__global__ __launch_bounds__(256, 3) void graphrec_agg_kernel(
    const int*   __restrict__ nodes,
    const int*   __restrict__ neigh_idx,
    const int*   __restrict__ neigh_len,
    const float* __restrict__ u2e,
    const float* __restrict__ b1,
    const float* __restrict__ b2,
    const float* __restrict__ W3,
    const float* __restrict__ b3,
    const bf16*  __restrict__ w1p,
    const bf16*  __restrict__ w2p,
    float*       __restrict__ out)
{
    __shared__ alignas(16) float eu[2 * EU_NODE_DW];       // 33280 B fp32 e_u
    __shared__ alignas(16) bf16  h1[2 * KN * H_STRIDE];    // 17408 B
    __shared__ alignas(16) float self_f[2 * D];            // 1024 B (A||B)
    __shared__ float lpart[2][4 * KN];                     // 1024 B
    __shared__ float att_s[2][KN];                         // 256 B
    __shared__ int   pidx[68];                             // [0:32) nA neigh, [32:64) nB neigh,
                                                           // [64],[65] self idx, [66],[67] len
    const int t    = threadIdx.x;
    const int lane = t & 63;
    const int wave = t >> 6;
    const int ln15 = lane & 15;
    const int quad = lane >> 4;
    const int nt0  = wave * 2;

    // loop-invariant scalars
    const float bias1_0 = b1[nt0 * 16 + ln15];
    const float bias1_1 = b1[(nt0 + 1) * 16 + ln15];
    const float bias2_0 = b2[nt0 * 16 + ln15];
    const float bias2_1 = b2[(nt0 + 1) * 16 + ln15];
    const float w3_0    = W3[nt0 * 16 + ln15];
    const float w3_1    = W3[(nt0 + 1) * 16 + ln15];
    const float b3v     = b3[0];

    // resident weight fragments (96 regs -> AGPR half of unified file)
    bf16x8 w1r[2][8];
    #pragma unroll
    for (int nt = 0; nt < 2; ++nt)
        #pragma unroll
        for (int ft = 0; ft < 8; ++ft)
            w1r[nt][ft] = *(const bf16x8*)(w1p + ((nt0 + nt) * 8 + ft) * 512 + lane * 8);
    bf16x8 w2r[2][4];
    #pragma unroll
    for (int nt = 0; nt < 2; ++nt)
        #pragma unroll
        for (int kt = 0; kt < 4; ++kt)
            w2r[nt][kt] = *(const bf16x8*)(w2p + ((nt0 + nt) * 4 + kt) * 512 + lane * 8);

    // iteration-0 index block
    if (t < 68) {
        int a = blockIdx.x * 8;
        const int* base; int off;
        if (t < 64)      { base = neigh_idx; off = (a + (t >> 5)) * KN + (t & 31); }
        else if (t < 66) { base = nodes;     off = a + (t & 1); }
        else             { base = neigh_len; off = a + (t & 1); }
        pidx[t] = base[off];
    }
    __syncthreads();

    for (int it = 0; it < ITERS; ++it) {
        const int nA   = blockIdx.x * 8 + it * 2;
        const int lenA = pidx[66];
        const int lenB = pidx[67];

        // ---- issue async gather: e_u (fp32) direct to LDS ----
        {
            const int half = lane >> 5;            // 0: row=chunk, 1: row=chunk+16
            const int colb = (lane & 31) << 4;     // 16 B per lane within row
            #pragma unroll
            for (int nd = 0; nd < 2; ++nd) {
                #pragma unroll
                for (int j = 0; j < 4; ++j) {
                    int chunk = wave * 4 + j;
                    int idx   = pidx[nd * KN + chunk + (half << 4)];
                    const char* src = (const char*)(u2e + (size_t)idx * D) + colb;
                    GL2LDS(src, eu + nd * EU_NODE_DW + chunk * CHUNK_DW);
                }
            }
            if (wave == 0) {                        // selfA (512 B) || selfB (512 B)
                int sidx = pidx[64 + half];
                const char* src = (const char*)(u2e + (size_t)sidx * D) + colb;
                GL2LDS(src, self_f);
            }
        }
        // ---- prefetch next iteration's index block into regs ----
        int pf = 0;
        {
            int a = blockIdx.x * 8 + (((it + 1) & 3) << 1);
            if (t < 68) {
                const int* base; int off;
                if (t < 64)      { base = neigh_idx; off = (a + (t >> 5)) * KN + (t & 31); }
                else if (t < 66) { base = nodes;     off = a + (t & 1); }
                else             { base = neigh_len; off = a + (t & 1); }
                pf = base[off];
            }
        }
        __syncthreads();   // barrier 1: gather resident
        if (t < 68) pidx[t] = pf;

        // ---- layer 1, both nodes: [32 x 256] @ [256 x 128] ----
        #pragma unroll
        for (int nd = 0; nd < 2; ++nd) {
            const float* euN = eu + nd * EU_NODE_DW;
            const float* sfN = self_f + nd * D;
            bf16* h1N = h1 + nd * KN * H_STRIDE;

            bf16x8 sa[4];
            #pragma unroll
            for (int i = 0; i < 4; ++i) {   // broadcast reads (same addr per quad)
                f32x4 u0 = *(const f32x4*)(sfN + i * 32 + quad * 8);
                f32x4 u1 = *(const f32x4*)(sfN + i * 32 + quad * 8 + 4);
                bf16x8 a;
                #pragma unroll
                for (int e = 0; e < 4; ++e) { a[e] = (bf16)u0[e]; a[4 + e] = (bf16)u1[e]; }
                sa[i] = a;
            }
            f32x4 c00 = {0.f,0.f,0.f,0.f}, c01 = c00, c10 = c00, c11 = c00;
            const int r0 = ln15 * CHUNK_DW;
            #pragma unroll
            for (int ft = 0; ft < 4; ++ft) {
                int off = ft * 32 + quad * 8;
                f32x4 u0 = *(const f32x4*)(euN + r0 + off);
                f32x4 u1 = *(const f32x4*)(euN + r0 + off + 4);
                f32x4 v0 = *(const f32x4*)(euN + r0 + 128 + off);   // row 16+ln15
                f32x4 v1 = *(const f32x4*)(euN + r0 + 128 + off + 4);
                bf16x8 a0, a1;
                #pragma unroll
                for (int e = 0; e < 4; ++e) {
                    a0[e] = (bf16)u0[e]; a0[4 + e] = (bf16)u1[e];
                    a1[e] = (bf16)v0[e]; a1[4 + e] = (bf16)v1[e];
                }
                c00 = MFMA(a0, w1r[0][ft], c00);
                c01 = MFMA(a0, w1r[1][ft], c01);
                c10 = MFMA(a1, w1r[0][ft], c10);
                c11 = MFMA(a1, w1r[1][ft], c11);
            }
            #pragma unroll
            for (int ft = 4; ft < 8; ++ft) {    // self half: same A both row-tiles
                bf16x8 a = sa[ft - 4];
                c00 = MFMA(a, w1r[0][ft], c00);
                c01 = MFMA(a, w1r[1][ft], c01);
                c10 = MFMA(a, w1r[0][ft], c10);
                c11 = MFMA(a, w1r[1][ft], c11);
            }
            #pragma unroll
            for (int r = 0; r < 4; ++r) {       // relu+bias -> bf16 LDS
                int row = quad * 4 + r;
                h1N[row * H_STRIDE + nt0 * 16 + ln15]              = (bf16)fmaxf(c00[r] + bias1_0, 0.f);
                h1N[row * H_STRIDE + (nt0 + 1) * 16 + ln15]        = (bf16)fmaxf(c01[r] + bias1_1, 0.f);
                h1N[(16 + row) * H_STRIDE + nt0 * 16 + ln15]       = (bf16)fmaxf(c10[r] + bias1_0, 0.f);
                h1N[(16 + row) * H_STRIDE + (nt0 + 1) * 16 + ln15] = (bf16)fmaxf(c11[r] + bias1_1, 0.f);
            }
        }
        __syncthreads();   // barrier 2

        // ---- layer 2 + fused logits, both nodes ----
        #pragma unroll
        for (int nd = 0; nd < 2; ++nd) {
            const bf16* h1N = h1 + nd * KN * H_STRIDE;
            f32x4 d00 = {0.f,0.f,0.f,0.f}, d01 = d00, d10 = d00, d11 = d00;
            #pragma unroll
            for (int kt = 0; kt < 4; ++kt) {
                bf16x8 a0 = *(const bf16x8*)(h1N + ln15 * H_STRIDE + kt * 32 + quad * 8);
                bf16x8 a1 = *(const bf16x8*)(h1N + (16 + ln15) * H_STRIDE + kt * 32 + quad * 8);
                d00 = MFMA(a0, w2r[0][kt], d00);
                d01 = MFMA(a0, w2r[1][kt], d01);
                d10 = MFMA(a1, w2r[0][kt], d10);
                d11 = MFMA(a1, w2r[1][kt], d11);
            }
            #pragma unroll
            for (int r = 0; r < 4; ++r) {   // h2 never materialized
                float p0 = w3_0 * fmaxf(d00[r] + bias2_0, 0.f)
                         + w3_1 * fmaxf(d01[r] + bias2_1, 0.f);
                float p1 = w3_0 * fmaxf(d10[r] + bias2_0, 0.f)
                         + w3_1 * fmaxf(d11[r] + bias2_1, 0.f);
                #pragma unroll
                for (int o = 1; o < 16; o <<= 1) {
                    p0 += __shfl_xor(p0, o);
                    p1 += __shfl_xor(p1, o);
                }
                if (ln15 == 0) {
                    lpart[nd][wave * KN + quad * 4 + r]      = p0;
                    lpart[nd][wave * KN + 16 + quad * 4 + r] = p1;
                }
            }
        }
        __syncthreads();   // barrier 3

        // ---- masked softmax: wave 0 -> node A, wave 1 -> node B ----
        if (wave < 2) {
            int nd = wave, k = lane & 31;
            float lg = lpart[nd][k] + lpart[nd][KN + k] + lpart[nd][2 * KN + k]
                     + lpart[nd][3 * KN + k] + b3v;
            int len = nd ? lenB : lenA;
            bool act = (lane < 32) && (k < len);
            float l = act ? lg : -1e30f;
            float m = l;
            #pragma unroll
            for (int o = 1; o < 32; o <<= 1) m = fmaxf(m, __shfl_xor(m, o));
            float e = act ? expf(l - m) : 0.f;
            float s = e;
            #pragma unroll
            for (int o = 1; o < 32; o <<= 1) s += __shfl_xor(s, o);
            if (lane < 32) att_s[nd][k] = (s > 0.f) ? (e / s) : 0.f;
        }
        __syncthreads();   // barrier 4

        // ---- aggregation (fp32), all 256 threads: t<128 node A, else node B ----
        {
            int nd = t >> 7, d = t & 127;
            const float* euN = eu + nd * EU_NODE_DW;
            float acc = 0.f;
            #pragma unroll
            for (int k = 0; k < KN; ++k)
                acc += att_s[nd][k] * euN[(k & 15) * CHUNK_DW + ((k >> 4) << 7) + d];
            float sf = self_f[nd * D + d];
            int len = nd ? lenB : lenA;
            out[(size_t)(nA + nd) * D + d] = (len > 0) ? 0.5f * (acc + sf) : sf;
        }
        __syncthreads();   // barrier 5: protect LDS for next iteration
    }
}

extern "C" void kernel_launch(void* const* d_in, const int* in_sizes, int n_in,
                              void* d_out, int out_size, void* d_ws, size_t ws_size,
                              hipStream_t stream) {
    const int*   nodes     = (const int*)d_in[0];
    const int*   neigh_idx = (const int*)d_in[1];
    const int*   neigh_len = (const int*)d_in[2];
    const float* u2e       = (const float*)d_in[3];
    const float* W1        = (const float*)d_in[4];
    const float* b1        = (const float*)d_in[5];
    const float* W2        = (const float*)d_in[6];
    const float* b2        = (const float*)d_in[7];
    const float* W3        = (const float*)d_in[8];
    const float* b3        = (const float*)d_in[9];
    float* out = (float*)d_out;

    bf16* w1p = (bf16*)d_ws;          // 32768 bf16 = 64 KB
    bf16* w2p = w1p + 32768;          // 16384 bf16 = 32 KB

    pack_weights_kernel<<<192, 256, 0, stream>>>(W1, W2, w1p, w2p);
    graphrec_agg_kernel<<<GRID, 256, 0, stream>>>(nodes, neigh_idx, neigh_len, u2e,
                                                  b1, b2, W3, b3, w1p, w2p, out);
}

// Round 4
// 233.287 us; speedup vs baseline: 1.3995x; 1.3995x over previous
//
#include <hip/hip_runtime.h>
#include <hip/hip_bf16.h>
#include <stdint.h>

#define KN 32
#define D  128
#define NNODES 20000
#define GRID 2500
#define ITERS 4            // 2 nodes/iter * 4 iters * 2500 blocks = 20000

typedef __bf16 bf16;
typedef __bf16 bf16x8 __attribute__((ext_vector_type(8)));
typedef float  f32x4  __attribute__((ext_vector_type(4)));

// e_u LDS layout: 16 chunks/node; chunk c = rows (c, c+16) back-to-back (1024 B,
// one global_load_lds wave-instruction) + 16 B pad -> 1040 B = 260 dw, 260%32=4
// -> bank granule rotates per chunk; b128 reads conflict-light.
#define CHUNK_DW 260
#define EU_NODE_DW (16 * CHUNK_DW)   // 4160 dw per node
#define H_STRIDE 136                 // bf16 elems; 68 dw, %32=4

#define GL2LDS(src, dst) __builtin_amdgcn_global_load_lds(                 \
    (const __attribute__((address_space(1))) void*)(src),                  \
    (__attribute__((address_space(3))) void*)(dst), 16, 0, 0)

#define MFMA(a, b, c) __builtin_amdgcn_mfma_f32_16x16x32_bf16((a), (b), (c), 0, 0, 0)

// ---------------------------------------------------------------------------
// Pack W1 (128x256) and W2 (128x128) fp32 -> bf16 in MFMA B-fragment order.
// B-frag for mfma_f32_16x16x32_bf16: lane holds B[k=quad*8+j][n=lane&15].
// ---------------------------------------------------------------------------
__global__ __launch_bounds__(256) void pack_weights_kernel(
    const float* __restrict__ W1, const float* __restrict__ W2,
    bf16* __restrict__ w1p, bf16* __restrict__ w2p)
{
    int t = blockIdx.x * 256 + threadIdx.x;
    if (t < 32768) {
        int j = t & 7, lane = (t >> 3) & 63, kt = (t >> 9) & 7, nt = t >> 12;
        int d = nt * 16 + (lane & 15);
        int f = kt * 32 + ((lane >> 4) << 3) + j;
        w1p[t] = (bf16)W1[d * 256 + f];
    } else if (t < 49152) {
        int u = t - 32768;
        int j = u & 7, lane = (u >> 3) & 63, kt = (u >> 9) & 3, nt = u >> 11;
        int e  = nt * 16 + (lane & 15);
        int dd = kt * 32 + ((lane >> 4) << 3) + j;
        w2p[u] = (bf16)W2[e * 128 + dd];
    }
}

// ---------------------------------------------------------------------------
// 256 threads = 4 waves; 2 nodes per iteration, 8 nodes per block.
// Weight B-fragments resident in registers. #pragma unroll 1 on it/nd loops:
// constant-bound full unroll was the round-3 spill trigger (205 MB scratch
// writes). Peak live regs ~150 < the (256,3) cap of ~170.
// ---------------------------------------------------------------------------
__global__ __launch_bounds__(256, 3) void graphrec_agg_kernel(
    const int*   __restrict__ nodes,
    const int*   __restrict__ neigh_idx,
    const int*   __restrict__ neigh_len,
    const float* __restrict__ u2e,
    const float* __restrict__ b1,
    const float* __restrict__ b2,
    const float* __restrict__ W3,
    const float* __restrict__ b3,
    const bf16*  __restrict__ w1p,
    const bf16*  __restrict__ w2p,
    float*       __restrict__ out)
{
    __shared__ alignas(16) float eu[2 * EU_NODE_DW];       // 33280 B fp32 e_u
    __shared__ alignas(16) bf16  h1[2 * KN * H_STRIDE];    // 17408 B
    __shared__ alignas(16) float self_f[2 * D];            // 1024 B (A||B)
    __shared__ float lpart[2][4 * KN];                     // 1024 B
    __shared__ float att_s[2][KN];                         // 256 B

    const int t    = threadIdx.x;
    const int lane = t & 63;
    const int wave = t >> 6;
    const int ln15 = lane & 15;
    const int quad = lane >> 4;
    const int nt0  = wave * 2;

    // loop-invariant per-lane scalars
    const float bias1_0 = b1[nt0 * 16 + ln15];
    const float bias1_1 = b1[(nt0 + 1) * 16 + ln15];
    const float bias2_0 = b2[nt0 * 16 + ln15];
    const float bias2_1 = b2[(nt0 + 1) * 16 + ln15];
    const float w3_0    = W3[nt0 * 16 + ln15];
    const float w3_1    = W3[(nt0 + 1) * 16 + ln15];
    const float b3v     = b3[0];

    // resident weight fragments: 96 regs
    bf16x8 w1r[2][8];
    #pragma unroll
    for (int nt = 0; nt < 2; ++nt)
        #pragma unroll
        for (int ft = 0; ft < 8; ++ft)
            w1r[nt][ft] = *(const bf16x8*)(w1p + ((nt0 + nt) * 8 + ft) * 512 + lane * 8);
    bf16x8 w2r[2][4];
    #pragma unroll
    for (int nt = 0; nt < 2; ++nt)
        #pragma unroll
        for (int kt = 0; kt < 4; ++kt)
            w2r[nt][kt] = *(const bf16x8*)(w2p + ((nt0 + nt) * 4 + kt) * 512 + lane * 8);

    #pragma unroll 1
    for (int it = 0; it < ITERS; ++it) {
        const int nA   = blockIdx.x * 8 + it * 2;
        const int lenA = neigh_len[nA];
        const int lenB = neigh_len[nA + 1];

        // ---- async gather: e_u fp32 direct to LDS ----
        // lanes 0-31 stage row `chunk`, lanes 32-63 row `chunk+16`; idx reads
        // are wave-broadcast (one 4B L1/L2 hit per half-wave).
        {
            const int half = lane >> 5;
            const int colb = (lane & 31) << 4;
            #pragma unroll
            for (int nd = 0; nd < 2; ++nd) {
                #pragma unroll
                for (int j = 0; j < 4; ++j) {
                    int chunk = wave * 4 + j;
                    int idx = neigh_idx[(nA + nd) * KN + chunk + (half << 4)];
                    const char* src = (const char*)(u2e + (size_t)idx * D) + colb;
                    GL2LDS(src, eu + nd * EU_NODE_DW + chunk * CHUNK_DW);
                }
            }
            if (wave == 0) {                        // selfA (512 B) || selfB (512 B)
                int sidx = nodes[nA + half];
                const char* src = (const char*)(u2e + (size_t)sidx * D) + colb;
                GL2LDS(src, self_f);
            }
        }
        __syncthreads();   // barrier 1: gather resident

        // ---- layer 1, both nodes: [32 x 256] @ [256 x 128] ----
        #pragma unroll 1
        for (int nd = 0; nd < 2; ++nd) {
            const float* euN = eu + nd * EU_NODE_DW;
            const float* sfN = self_f + nd * D;
            bf16* h1N = h1 + nd * KN * H_STRIDE;

            f32x4 c00 = {0.f,0.f,0.f,0.f}, c01 = c00, c10 = c00, c11 = c00;
            const int r0 = ln15 * CHUNK_DW;
            #pragma unroll
            for (int ft = 0; ft < 4; ++ft) {
                int off = ft * 32 + quad * 8;
                f32x4 u0 = *(const f32x4*)(euN + r0 + off);
                f32x4 u1 = *(const f32x4*)(euN + r0 + off + 4);
                f32x4 v0 = *(const f32x4*)(euN + r0 + 128 + off);   // row 16+ln15
                f32x4 v1 = *(const f32x4*)(euN + r0 + 128 + off + 4);
                bf16x8 a0, a1;
                #pragma unroll
                for (int e = 0; e < 4; ++e) {
                    a0[e] = (bf16)u0[e]; a0[4 + e] = (bf16)u1[e];
                    a1[e] = (bf16)v0[e]; a1[4 + e] = (bf16)v1[e];
                }
                c00 = MFMA(a0, w1r[0][ft], c00);
                c01 = MFMA(a0, w1r[1][ft], c01);
                c10 = MFMA(a1, w1r[0][ft], c10);
                c11 = MFMA(a1, w1r[1][ft], c11);
            }
            #pragma unroll
            for (int ft = 4; ft < 8; ++ft) {    // self half: same A both row-tiles,
                int off = (ft - 4) * 32 + quad * 8;          // converted on the fly
                f32x4 u0 = *(const f32x4*)(sfN + off);
                f32x4 u1 = *(const f32x4*)(sfN + off + 4);
                bf16x8 a;
                #pragma unroll
                for (int e = 0; e < 4; ++e) { a[e] = (bf16)u0[e]; a[4 + e] = (bf16)u1[e]; }
                c00 = MFMA(a, w1r[0][ft], c00);
                c01 = MFMA(a, w1r[1][ft], c01);
                c10 = MFMA(a, w1r[0][ft], c10);
                c11 = MFMA(a, w1r[1][ft], c11);
            }
            #pragma unroll
            for (int r = 0; r < 4; ++r) {       // relu+bias -> bf16 LDS
                int row = quad * 4 + r;
                h1N[row * H_STRIDE + nt0 * 16 + ln15]              = (bf16)fmaxf(c00[r] + bias1_0, 0.f);
                h1N[row * H_STRIDE + (nt0 + 1) * 16 + ln15]        = (bf16)fmaxf(c01[r] + bias1_1, 0.f);
                h1N[(16 + row) * H_STRIDE + nt0 * 16 + ln15]       = (bf16)fmaxf(c10[r] + bias1_0, 0.f);
                h1N[(16 + row) * H_STRIDE + (nt0 + 1) * 16 + ln15] = (bf16)fmaxf(c11[r] + bias1_1, 0.f);
            }
        }
        __syncthreads();   // barrier 2

        // ---- layer 2 + fused logits, both nodes ----
        #pragma unroll 1
        for (int nd = 0; nd < 2; ++nd) {
            const bf16* h1N = h1 + nd * KN * H_STRIDE;
            f32x4 d00 = {0.f,0.f,0.f,0.f}, d01 = d00, d10 = d00, d11 = d00;
            #pragma unroll
            for (int kt = 0; kt < 4; ++kt) {
                bf16x8 a0 = *(const bf16x8*)(h1N + ln15 * H_STRIDE + kt * 32 + quad * 8);
                bf16x8 a1 = *(const bf16x8*)(h1N + (16 + ln15) * H_STRIDE + kt * 32 + quad * 8);
                d00 = MFMA(a0, w2r[0][kt], d00);
                d01 = MFMA(a0, w2r[1][kt], d01);
                d10 = MFMA(a1, w2r[0][kt], d10);
                d11 = MFMA(a1, w2r[1][kt], d11);
            }
            #pragma unroll
            for (int r = 0; r < 4; ++r) {   // h2 never materialized
                float p0 = w3_0 * fmaxf(d00[r] + bias2_0, 0.f)
                         + w3_1 * fmaxf(d01[r] + bias2_1, 0.f);
                float p1 = w3_0 * fmaxf(d10[r] + bias2_0, 0.f)
                         + w3_1 * fmaxf(d11[r] + bias2_1, 0.f);
                #pragma unroll
                for (int o = 1; o < 16; o <<= 1) {
                    p0 += __shfl_xor(p0, o);
                    p1 += __shfl_xor(p1, o);
                }
                if (ln15 == 0) {
                    lpart[nd][wave * KN + quad * 4 + r]      = p0;
                    lpart[nd][wave * KN + 16 + quad * 4 + r] = p1;
                }
            }
        }
        __syncthreads();   // barrier 3

        // ---- masked softmax: wave 0 -> node A, wave 1 -> node B ----
        if (wave < 2) {
            int nd = wave, k = lane & 31;
            float lg = lpart[nd][k] + lpart[nd][KN + k] + lpart[nd][2 * KN + k]
                     + lpart[nd][3 * KN + k] + b3v;
            int len = nd ? lenB : lenA;
            bool act = (lane < 32) && (k < len);
            float l = act ? lg : -1e30f;
            float m = l;
            #pragma unroll
            for (int o = 1; o < 32; o <<= 1) m = fmaxf(m, __shfl_xor(m, o));
            float e = act ? expf(l - m) : 0.f;
            float s = e;
            #pragma unroll
            for (int o = 1; o < 32; o <<= 1) s += __shfl_xor(s, o);
            if (lane < 32) att_s[nd][k] = (s > 0.f) ? (e / s) : 0.f;
        }
        __syncthreads();   // barrier 4

        // ---- aggregation (fp32), all 256 threads: t<128 node A, else node B ----
        {
            int nd = t >> 7, d = t & 127;
            const float* euN = eu + nd * EU_NODE_DW;
            float acc = 0.f;
            #pragma unroll
            for (int k = 0; k < KN; ++k)
                acc += att_s[nd][k] * euN[(k & 15) * CHUNK_DW + ((k >> 4) << 7) + d];
            float sf = self_f[nd * D + d];
            int len = nd ? lenB : lenA;
            out[(size_t)(nA + nd) * D + d] = (len > 0) ? 0.5f * (acc + sf) : sf;
        }
        __syncthreads();   // barrier 5: protect LDS for next iteration
    }
}

extern "C" void kernel_launch(void* const* d_in, const int* in_sizes, int n_in,
                              void* d_out, int out_size, void* d_ws, size_t ws_size,
                              hipStream_t stream) {
    const int*   nodes     = (const int*)d_in[0];
    const int*   neigh_idx = (const int*)d_in[1];
    const int*   neigh_len = (const int*)d_in[2];
    const float* u2e       = (const float*)d_in[3];
    const float* W1        = (const float*)d_in[4];
    const float* b1        = (const float*)d_in[5];
    const float* W2        = (const float*)d_in[6];
    const float* b2        = (const float*)d_in[7];
    const float* W3        = (const float*)d_in[8];
    const float* b3        = (const float*)d_in[9];
    float* out = (float*)d_out;

    bf16* w1p = (bf16*)d_ws;          // 32768 bf16 = 64 KB
    bf16* w2p = w1p + 32768;          // 16384 bf16 = 32 KB

    pack_weights_kernel<<<192, 256, 0, stream>>>(W1, W2, w1p, w2p);
    graphrec_agg_kernel<<<GRID, 256, 0, stream>>>(nodes, neigh_idx, neigh_len, u2e,
                                                  b1, b2, W3, b3, w1p, w2p, out);
}